// Round 5
// baseline (1266.096 us; speedup 1.0000x reference)
//
#include <hip/hip_runtime.h>
#include <hip/hip_bf16.h>
#include <cstdint>

// LISTA: Z = eta(X@We^T + Z@S^T), 16 unrolled steps. B=16384, n=256, m=1024.
// 256x256-tile, 8 waves (2Mx4N), BK=64, 128 KiB double-buffered LDS (swz2
// XOR-swizzle, conflict-free), counted-vmcnt deep prefetch, one barrier per
// phase, mfma 32x32x16, LDS-transposed bf16 epilogue.
// Each step computes C = [X,Z] @ [We,S]^T (K=1280, NT=20) - no fp32 B matrix.
// Round-5 change vs round-4: REGISTER-LEVEL FRAGMENT PIPELINING.
//  Phase p issues ds_reads for phase p+1's fragments, then waits a COUNTED
//  lgkmcnt(N_issued) (drains only phase p's fragments, which have had a full
//  phase to complete) -> LDS latency no longer serialized with MFMA.
//  Requires: 2 A-fragment sets (afE/afO) + bf0/bf1; odd-tile quadrant order
//  flipped to (01,00,10,11) so no phase's read-target collides with its MFMA
//  operands; stage schedule shifted one phase where needed (strict
//  drain->barrier->overwrite ordering); vmcnt(6) at p3/p7 lands each tile one
//  phase before its first early read.
// Per-phase ledger (steady window; tiles a=buf0,b=buf1; stage c->buf0,d->buf1):
//  p1: rd bf1<-a.Bh1[4]  st -            w lgkm(4)  mfma Q00(afE,bf0)
//  p2: rd afO<-a.Ah1[8]  st c.Ah0,c.Bh0 w lgkm(8)  mfma Q01(afE,bf1)
//  p3: rd -              st c.Bh1       w lgkm(0)  mfma Q11(afO,bf1) vm(6)
//  p4: rd afE<-b.Ah0,bf1<-b.Bh1[12] st c.Ah1       mfma Q10(afO,bf0)
//  p5: rd bf0<-b.Bh0[4]  st -           w lgkm(4)  mfma Q01(afE,bf1)
//  p6: rd afO<-b.Ah1[8]  st d.Ah0,d.Bh1 w lgkm(8)  mfma Q00(afE,bf0)
//  p7: rd -              st d.Bh0       w lgkm(0)  mfma Q10(afO,bf0) vm(6)
//  p8: rd afE<-c.Ah0,bf0<-c.Bh0[12] st d.Ah1       mfma Q11(afO,bf1)

typedef __attribute__((ext_vector_type(8))) short short8;    // 8 x bf16
typedef __attribute__((ext_vector_type(16))) float f32x16;   // 32x32 mfma acc

__device__ __forceinline__ void g2lds16(const void* g, void* l) {
    __builtin_amdgcn_global_load_lds(
        (const __attribute__((address_space(1))) uint32_t*)(uintptr_t)g,
        (__attribute__((address_space(3))) uint32_t*)(uintptr_t)l,
        16, 0, 0);
}

#define VM6  asm volatile("s_waitcnt vmcnt(6)" ::: "memory")
#define VM8  asm volatile("s_waitcnt vmcnt(8)" ::: "memory")
#define VM0  asm volatile("s_waitcnt vmcnt(0)" ::: "memory")
#define WL4  asm volatile("s_waitcnt lgkmcnt(4)" ::: "memory")
#define WL8  asm volatile("s_waitcnt lgkmcnt(8)" ::: "memory")
#define WL0  asm volatile("s_waitcnt lgkmcnt(0)" ::: "memory")
#define NOPX ((void)0)

// A-frags into set AF: 2 m-frags x 4 k-slices from A-half HH of buffer CB.
#define LOAD_A(CB, HH, AF) do { \
    const char* ap_ = &lds[CB][0][HH][0] + arow; \
    _Pragma("unroll") \
    for (int mf_ = 0; mf_ < 2; ++mf_) { \
        AF[mf_][0] = *(const short8*)(ap_ + mf_*4096 + ck0); \
        AF[mf_][1] = *(const short8*)(ap_ + mf_*4096 + ck1); \
        AF[mf_][2] = *(const short8*)(ap_ + mf_*4096 + ck2); \
        AF[mf_][3] = *(const short8*)(ap_ + mf_*4096 + ck3); \
    } } while (0)

// B-frag into set BF: 1 n-frag x 4 k-slices from B-half HH of buffer CB.
#define LOAD_B(CB, HH, BF) do { \
    const char* bp_ = &lds[CB][1][HH][0] + brow; \
    BF[0] = *(const short8*)(bp_ + ck0); \
    BF[1] = *(const short8*)(bp_ + ck1); \
    BF[2] = *(const short8*)(bp_ + ck2); \
    BF[3] = *(const short8*)(bp_ + ck3); \
} while (0)

// One phase: {next-phase ds-reads | stage issue} ; counted lgkm ; 8 MFMA ;
// [vmcnt] ; barrier.  Reads target regs NOT used by this phase's MFMA.
#define PHASE(RD, STG, WAITX, QM, QN, AF, BF, VMW) do { \
    RD; STG; \
    WAITX; \
    __builtin_amdgcn_sched_barrier(0); \
    __builtin_amdgcn_s_setprio(1); \
    _Pragma("unroll") \
    for (int kk_ = 0; kk_ < 4; ++kk_) \
    _Pragma("unroll") \
    for (int mf_ = 0; mf_ < 2; ++mf_) \
        acc[(QM)*2+mf_][(QN)] = __builtin_amdgcn_mfma_f32_32x32x16_bf16( \
            AF[mf_][kk_], BF[kk_], acc[(QM)*2+mf_][(QN)], 0, 0, 0); \
    __builtin_amdgcn_s_setprio(0); \
    VMW; \
    __builtin_amdgcn_s_barrier(); \
    __builtin_amdgcn_sched_barrier(0); \
} while (0)

// Tiles 0..NTX-1 from (Ax,Wx), stride NTX*128 B; NTX.. from (Az,Wz), NTZ*128 B.
// C[i,j] = sum_k A[i,k]*W[j,k]; output eta(C) (bf16, or fp32 if LAST).
template<int NTX, int NTZ, bool LAST>
__global__ void __launch_bounds__(512, 2)
lista_step(const unsigned short* __restrict__ Ax,
           const unsigned short* __restrict__ Wx,
           const unsigned short* __restrict__ Az,
           const unsigned short* __restrict__ Wz,
           const float* __restrict__ theta,
           unsigned short* __restrict__ Zout,
           float* __restrict__ Fout)
{
    constexpr int NT  = NTX + NTZ;     // total K-tiles of 64
    constexpr int NI  = NT / 2;        // windows (2 K-tiles each)
    constexpr int KBX = NTX * 128;     // X/We row stride (bytes)
    constexpr int KBZ = NTZ * 128;     // Z/S  row stride (bytes)

    // [buf][A=0/B=1][half][16KB]; half = permuted 128-row group so each half
    // is read in exactly one phase (A: bit6 of row; B: bit5 of row).
    __shared__ __align__(128) char lds[2][2][2][16384];

    const int t    = threadIdx.x;      // 0..511
    const int lane = t & 63;
    const int wave = t >> 6;           // 0..7
    const int wm   = wave >> 2;        // 0..1  (M half)
    const int wn   = wave & 3;         // 0..3  (N quarter)
    const int bm   = blockIdx.x;       // 0..63
    const int bn   = blockIdx.y;       // 0..3

    const char* Xb = (const char*)Ax + (size_t)bm * 256 * KBX;
    const char* Wb = (const char*)Wx + (size_t)bn * 256 * KBX;
    const char* Zb = (const char*)Az + (size_t)bm * 256 * KBZ;
    const char* Sb = (const char*)Wz + (size_t)bn * 256 * KBZ;

    // staging: thread t, call c handles linear chunk I = c*512+t -> compacted
    // row rho = I>>3, slot = I&7; slot holds global k-chunk slot ^ swz2(rho),
    // swz2(r) = (r ^ (r>>2)) & 7.
    const int u    = t >> 3;                       // 0..63
    const int gb16 = ((t & 7) ^ ((u ^ (u >> 2)) & 7)) << 4;
    const int rA0  = u;                            // A: row = rA0+64h (+128 c=1)
    const int rB0  = (u & 31) + 2 * (u & 32);      // B: row = rB0+32h (+128 c=1)

    // fragment-read constants (32x32x16: lane -> row=lane&31, k=(lane>>5)*8+e)
    const int r31  = lane & 31;
    const int l5   = lane >> 5;                    // k-half
    const int sw   = (r31 ^ (r31 >> 2)) & 7;       // swz2 of compacted row
    const int ck0  = ((0 + l5) ^ sw) << 4;
    const int ck1  = ((2 + l5) ^ sw) << 4;
    const int ck2  = ((4 + l5) ^ sw) << 4;
    const int ck3  = ((6 + l5) ^ sw) << 4;
    const int arow = (wm * 64 + r31) * 128;        // A compacted-row byte base
    const int brow = (wn * 32 + r31) * 128;        // B compacted-row byte base

    f32x16 acc[4][2];
#pragma unroll
    for (int i = 0; i < 4; ++i)
#pragma unroll
        for (int j = 0; j < 2; ++j)
#pragma unroll
            for (int r = 0; r < 16; ++r) acc[i][j][r] = 0.f;

    short8 afE[2][4], afO[2][4], bf0[4], bf1[4];

    auto STAGE_A = [&](int buf, int h, int kt) {
        const char* base; int kb, ko;
        if (NTZ == 0 || kt < NTX) { base = Xb; kb = KBX; ko = kt * 128; }
        else                      { base = Zb; kb = KBZ; ko = (kt - NTX) * 128; }
        char* lp = &lds[buf][0][h][0] + t * 16;
        const size_t go = (size_t)(rA0 + 64 * h) * kb + ko + gb16;
        g2lds16(base + go, lp);
        g2lds16(base + go + (size_t)128 * kb, lp + 8192);
    };
    auto STAGE_B = [&](int buf, int h, int kt) {
        const char* base; int kb, ko;
        if (NTZ == 0 || kt < NTX) { base = Wb; kb = KBX; ko = kt * 128; }
        else                      { base = Sb; kb = KBZ; ko = (kt - NTX) * 128; }
        char* lp = &lds[buf][1][h][0] + t * 16;
        const size_t go = (size_t)(rB0 + 32 * h) * kb + ko + gb16;
        g2lds16(base + go, lp);
        g2lds16(base + go + (size_t)128 * kb, lp + 8192);
    };

    // prologue: stage tile0 (buf0) + tile1 (buf1) fully; drain tile0 (oldest
    // 8 of 16); barrier; then pre-read p1's fragments (afE,bf0 <- tile0 h0).
    STAGE_A(0, 0, 0); STAGE_B(0, 0, 0); STAGE_A(0, 1, 0); STAGE_B(0, 1, 0);
    STAGE_A(1, 0, 1); STAGE_B(1, 0, 1); STAGE_A(1, 1, 1); STAGE_B(1, 1, 1);
    VM8;
    __builtin_amdgcn_s_barrier();
    __builtin_amdgcn_sched_barrier(0);
    LOAD_A(0, 0, afE); LOAD_B(0, 0, bf0);

    // main loop (see ledger in header). vmcnt at p3/p7: outstanding =
    // prev-tile 8 + new 6 = 14 -> vmcnt(6) drains exactly the tile needed
    // one phase later. All stage-overwrites occur >=1 phase after the
    // counted-wait + barrier that drains the region's last reads.
#pragma unroll 1
    for (int it = 0; it < NI - 1; ++it) {
        const int c = 2 * it + 2, d = 2 * it + 3;
        PHASE(LOAD_B(0,1,bf1), NOPX,                             WL4,  0,0, afE, bf0, NOPX);
        PHASE(LOAD_A(0,1,afO), (STAGE_A(0,0,c), STAGE_B(0,0,c)), WL8,  0,1, afE, bf1, NOPX);
        PHASE(NOPX,            STAGE_B(0,1,c),                   WL0,  1,1, afO, bf1, VM6);
        PHASE(LOAD_A(1,0,afE); LOAD_B(1,1,bf1), STAGE_A(0,1,c),  NOPX, 1,0, afO, bf0, NOPX);
        PHASE(LOAD_B(1,0,bf0), NOPX,                             WL4,  0,1, afE, bf1, NOPX);
        PHASE(LOAD_A(1,1,afO), (STAGE_A(1,0,d), STAGE_B(1,1,d)), WL8,  0,0, afE, bf0, NOPX);
        PHASE(NOPX,            STAGE_B(1,0,d),                   WL0,  1,0, afO, bf0, VM6);
        PHASE(LOAD_A(0,0,afE); LOAD_B(0,0,bf0), STAGE_A(1,1,d),  NOPX, 1,1, afO, bf1, NOPX);
    }
    {   // last window: no stages; VM0 at p3 drains tile NT-1; no p8 pre-read.
        PHASE(LOAD_B(0,1,bf1), NOPX,            WL4,  0,0, afE, bf0, NOPX);
        PHASE(LOAD_A(0,1,afO), NOPX,            WL8,  0,1, afE, bf1, NOPX);
        PHASE(NOPX,            NOPX,            WL0,  1,1, afO, bf1, VM0);
        PHASE(LOAD_A(1,0,afE); LOAD_B(1,1,bf1), NOPX, NOPX, 1,0, afO, bf0, NOPX);
        PHASE(LOAD_B(1,0,bf0), NOPX,            WL4,  0,1, afE, bf1, NOPX);
        PHASE(LOAD_A(1,1,afO), NOPX,            WL8,  0,0, afE, bf0, NOPX);
        PHASE(NOPX,            NOPX,            WL0,  1,0, afO, bf0, NOPX);
        PHASE(NOPX,            NOPX,            NOPX, 1,1, afO, bf1, NOPX);
    }

    // epilogue. 32x32 C/D: col = lane&31, row = (reg&3)+8*(reg>>2)+4*(lane>>5)
    const int colb = bn * 256 + wn * 64 + r31;
    const int rowb = bm * 256 + wm * 128;
    const float th0 = theta[colb];
    const float th1 = theta[colb + 32];

    if constexpr (LAST) {
        // fp32 direct: 32 lanes x 4B = full 128B line per row-chunk.
#pragma unroll
        for (int MF = 0; MF < 4; ++MF)
#pragma unroll
        for (int reg = 0; reg < 16; ++reg) {
            const int rrow = rowb + MF * 32 + (reg & 3) + 8 * (reg >> 2) + 4 * l5;
#pragma unroll
            for (int h = 0; h < 2; ++h) {
                const float c = acc[MF][h][reg];
                const float a = fabsf(c) - (h ? th1 : th0);
                const float z = a > 0.f ? (c > 0.f ? a : -a) : 0.f;
                Fout[(size_t)rrow * 1024 + colb + h * 32] = z;
            }
        }
    } else {
        // bf16 via per-wave 16KB LDS transpose slab; readback row-linear ->
        // each global store = 8 rows x 128B full lines (no write RMW).
        char* slab = &lds[0][0][0][0] + wave * 16384;
#pragma unroll
        for (int MF = 0; MF < 4; ++MF)
#pragma unroll
        for (int h = 0; h < 2; ++h)
#pragma unroll
        for (int reg = 0; reg < 16; ++reg) {
            const int row = MF * 32 + (reg & 3) + 8 * (reg >> 2) + 4 * l5;
            const int cb  = (h * 64 + r31 * 2) ^ ((row & 7) << 4);
            const float c = acc[MF][h][reg];
            const float a = fabsf(c) - (h ? th1 : th0);
            const float z = a > 0.f ? (c > 0.f ? a : -a) : 0.f;
            __hip_bfloat16 hb = __float2bfloat16(z);
            *(unsigned short*)(slab + row * 128 + cb) = *(const unsigned short*)&hb;
        }
        __builtin_amdgcn_sched_barrier(0);
#pragma unroll
        for (int i = 0; i < 16; ++i) {
            const int r = i * 8 + (lane >> 3);
            const short8 v = *(const short8*)(slab + r * 128 + (((lane & 7) ^ (r & 7)) << 4));
            char* gp = (char*)Zout + (size_t)(rowb + r) * 2048
                     + bn * 512 + wn * 128 + (lane & 7) * 16;
            *(short8*)gp = v;
        }
    }
}

__global__ void __launch_bounds__(256)
cvt4(const float* __restrict__ s, unsigned short* __restrict__ d, int n4)
{
    const int i = blockIdx.x * blockDim.x + threadIdx.x;
    if (i < n4) {
        const float4 v = ((const float4*)s)[i];
        ushort4 o;
        __hip_bfloat16 b;
        b = __float2bfloat16(v.x); o.x = *(unsigned short*)&b;
        b = __float2bfloat16(v.y); o.y = *(unsigned short*)&b;
        b = __float2bfloat16(v.z); o.z = *(unsigned short*)&b;
        b = __float2bfloat16(v.w); o.w = *(unsigned short*)&b;
        ((ushort4*)d)[i] = o;
    }
}

extern "C" void kernel_launch(void* const* d_in, const int* in_sizes, int n_in,
                              void* d_out, int out_size, void* d_ws, size_t ws_size,
                              hipStream_t stream) {
    (void)in_sizes; (void)n_in; (void)out_size; (void)ws_size;
    const float* X     = (const float*)d_in[0];  // 16384 x 256
    const float* We    = (const float*)d_in[1];  // 1024 x 256
    const float* S     = (const float*)d_in[2];  // 1024 x 1024
    const float* theta = (const float*)d_in[3];  // 1024
    float* out = (float*)d_out;                  // 16384 x 1024 fp32

    char* ws = (char*)d_ws;
    unsigned short* S_bf  = (unsigned short*)(ws);                           //  2 MB
    unsigned short* X_bf  = (unsigned short*)(ws + (size_t)2  * 1048576);    //  8 MB
    unsigned short* We_bf = (unsigned short*)(ws + (size_t)10 * 1048576);    // 0.5 MB
    unsigned short* Za    = (unsigned short*)(ws + (size_t)11 * 1048576);    // 32 MB
    unsigned short* Zb    = (unsigned short*)(ws + (size_t)43 * 1048576);    // 32 MB (total 75 MB)

    cvt4<<<dim3(1024), dim3(256), 0, stream>>>(S,  S_bf,  1024 * 1024 / 4);
    cvt4<<<dim3(4096), dim3(256), 0, stream>>>(X,  X_bf,  16384 * 256 / 4);
    cvt4<<<dim3(256),  dim3(256), 0, stream>>>(We, We_bf, 1024 * 256 / 4);

    const dim3 grid(64, 4), blk(512);

    // Z0 = eta(X @ We^T)            (K = 256)
    lista_step<4, 0, false><<<grid, blk, 0, stream>>>(
        X_bf, We_bf, nullptr, nullptr, theta, Za, nullptr);

    // steps 1..15: Z = eta([X,Z] @ [We,S]^T)   (K = 1280), ping-pong bf16
    unsigned short* zin = Za;
    unsigned short* zout = Zb;
    for (int tstep = 1; tstep <= 15; ++tstep) {
        lista_step<4, 16, false><<<grid, blk, 0, stream>>>(
            X_bf, We_bf, zin, S_bf, theta, zout, nullptr);
        unsigned short* tmp = zin; zin = zout; zout = tmp;
    }
    // step 16: write fp32 output directly
    lista_step<4, 16, true><<<grid, blk, 0, stream>>>(
        X_bf, We_bf, zin, S_bf, theta, nullptr, out);
}

// Round 6
// 804.061 us; speedup vs baseline: 1.5746x; 1.5746x over previous
//
#include <hip/hip_runtime.h>
#include <hip/hip_bf16.h>
#include <cstdint>

// LISTA: Z = eta(X@We^T + Z@S^T), 16 unrolled steps. B=16384, n=256, m=1024.
// 256x256-tile, 8 waves (2Mx4N), BK=64, 128 KiB double-buffered LDS (swz2
// XOR-swizzle, conflict-free), counted-vmcnt deep prefetch, one barrier per
// phase, mfma 32x32x16, LDS-transposed bf16 epilogue.
// Each step computes C = [X,Z] @ [We,S]^T (K=1280, NT=20) - no fp32 B matrix.
// Round-6 vs round-5: round-5's dual A-set spilled (~130 arch regs > 128 cap;
// FETCH/WRITE +16MB scratch). Keep B-pipelining, drop to a SINGLE A-set with
// A-half-major quadrant order (Q00,Q01 | Q10,Q11): af reloaded in-phase at
// half switches (4 of 8 phases expose ~200cyc A-read latency), bf0/bf1 still
// read one phase ahead. Fragments = 64 arch regs -> fits 128-arch budget
// (acc 128 lives in AGPR; 256 total = 2 waves/SIMD cap).
// Steady window (tiles a=buf0,b=buf1; stage c->buf0 @p2/p4, d->buf1 @p6/p8):
//  p1: rd af<-a.Ah0 + bf1<-a.Bh1 [12]; WL0;  Q00(af,bf0)
//  p2: st c.Ah0,c.Bh0,c.Bh1 [6];       -  ;  Q01(af,bf1)
//  p3: rd af<-a.Ah1 [8];               WL0;  Q10(af,bf0)   VM6 (b lands)
//  p4: rd bf0<-b.Bh0 [4]; st c.Ah1[2]; -  ;  Q11(af,bf1)
//  p5: rd af<-b.Ah0 + bf1<-b.Bh1 [12]; WL0;  Q00(af,bf0)
//  p6: st d.Ah0,d.Bh0,d.Bh1 [6];       -  ;  Q01(af,bf1)
//  p7: rd af<-b.Ah1 [8];               WL0;  Q10(af,bf0)   VM6 (c lands)
//  p8: rd bf0<-c.Bh0 [4]; st d.Ah1[2]; -  ;  Q11(af,bf1)
// vm ledger: start 8(b); p2 +6=14; p3 VM6 drains b; p4 +2=8; p6 +6=14;
// p7 VM6 drains c; p8 +2=8 = next window's b.  Overwrite rule verified:
// every stage >=1 phase after the WL0+barrier draining its region's last read.

typedef __attribute__((ext_vector_type(8))) short short8;    // 8 x bf16
typedef __attribute__((ext_vector_type(16))) float f32x16;   // 32x32 mfma acc

__device__ __forceinline__ void g2lds16(const void* g, void* l) {
    __builtin_amdgcn_global_load_lds(
        (const __attribute__((address_space(1))) uint32_t*)(uintptr_t)g,
        (__attribute__((address_space(3))) uint32_t*)(uintptr_t)l,
        16, 0, 0);
}

#define VM6  asm volatile("s_waitcnt vmcnt(6)" ::: "memory")
#define VM8  asm volatile("s_waitcnt vmcnt(8)" ::: "memory")
#define VM0  asm volatile("s_waitcnt vmcnt(0)" ::: "memory")
#define WL0  asm volatile("s_waitcnt lgkmcnt(0)" ::: "memory")
#define NOPX ((void)0)

// A-frags into af: 2 m-frags x 4 k-slices from A-half HH of buffer CB.
#define LOAD_A(CB, HH) do { \
    const char* ap_ = &lds[CB][0][HH][0] + arow; \
    _Pragma("unroll") \
    for (int mf_ = 0; mf_ < 2; ++mf_) { \
        af[mf_][0] = *(const short8*)(ap_ + mf_*4096 + ck0); \
        af[mf_][1] = *(const short8*)(ap_ + mf_*4096 + ck1); \
        af[mf_][2] = *(const short8*)(ap_ + mf_*4096 + ck2); \
        af[mf_][3] = *(const short8*)(ap_ + mf_*4096 + ck3); \
    } } while (0)

// B-frag into set BF: 1 n-frag x 4 k-slices from B-half HH of buffer CB.
#define LOAD_B(CB, HH, BF) do { \
    const char* bp_ = &lds[CB][1][HH][0] + brow; \
    BF[0] = *(const short8*)(bp_ + ck0); \
    BF[1] = *(const short8*)(bp_ + ck1); \
    BF[2] = *(const short8*)(bp_ + ck2); \
    BF[3] = *(const short8*)(bp_ + ck3); \
} while (0)

// One phase: {ds-reads | stage issue} ; [counted lgkm] ; 8 MFMA ; [vmcnt] ; bar
#define PHASE(RD, STG, WAITX, QM, QN, BF, VMW) do { \
    RD; STG; \
    WAITX; \
    __builtin_amdgcn_sched_barrier(0); \
    __builtin_amdgcn_s_setprio(1); \
    _Pragma("unroll") \
    for (int kk_ = 0; kk_ < 4; ++kk_) \
    _Pragma("unroll") \
    for (int mf_ = 0; mf_ < 2; ++mf_) \
        acc[(QM)*2+mf_][(QN)] = __builtin_amdgcn_mfma_f32_32x32x16_bf16( \
            af[mf_][kk_], BF[kk_], acc[(QM)*2+mf_][(QN)], 0, 0, 0); \
    __builtin_amdgcn_s_setprio(0); \
    VMW; \
    __builtin_amdgcn_s_barrier(); \
    __builtin_amdgcn_sched_barrier(0); \
} while (0)

// Tiles 0..NTX-1 from (Ax,Wx), stride NTX*128 B; NTX.. from (Az,Wz), NTZ*128 B.
// C[i,j] = sum_k A[i,k]*W[j,k]; output eta(C) (bf16, or fp32 if LAST).
template<int NTX, int NTZ, bool LAST>
__global__ void __launch_bounds__(512, 2)
lista_step(const unsigned short* __restrict__ Ax,
           const unsigned short* __restrict__ Wx,
           const unsigned short* __restrict__ Az,
           const unsigned short* __restrict__ Wz,
           const float* __restrict__ theta,
           unsigned short* __restrict__ Zout,
           float* __restrict__ Fout)
{
    constexpr int NT  = NTX + NTZ;     // total K-tiles of 64
    constexpr int NI  = NT / 2;        // windows (2 K-tiles each)
    constexpr int KBX = NTX * 128;     // X/We row stride (bytes)
    constexpr int KBZ = NTZ * 128;     // Z/S  row stride (bytes)

    // [buf][A=0/B=1][half][16KB]; half = permuted 128-row group so each half
    // is read in exactly one phase (A: bit6 of row; B: bit5 of row).
    __shared__ __align__(128) char lds[2][2][2][16384];

    const int t    = threadIdx.x;      // 0..511
    const int lane = t & 63;
    const int wave = t >> 6;           // 0..7
    const int wm   = wave >> 2;        // 0..1  (M half)
    const int wn   = wave & 3;         // 0..3  (N quarter)
    const int bm   = blockIdx.x;       // 0..63
    const int bn   = blockIdx.y;       // 0..3

    const char* Xb = (const char*)Ax + (size_t)bm * 256 * KBX;
    const char* Wb = (const char*)Wx + (size_t)bn * 256 * KBX;
    const char* Zb = (const char*)Az + (size_t)bm * 256 * KBZ;
    const char* Sb = (const char*)Wz + (size_t)bn * 256 * KBZ;

    // staging: thread t, call c handles linear chunk I = c*512+t -> compacted
    // row rho = I>>3, slot = I&7; slot holds global k-chunk slot ^ swz2(rho),
    // swz2(r) = (r ^ (r>>2)) & 7.
    const int u    = t >> 3;                       // 0..63
    const int gb16 = ((t & 7) ^ ((u ^ (u >> 2)) & 7)) << 4;
    const int rA0  = u;                            // A: row = rA0+64h (+128 c=1)
    const int rB0  = (u & 31) + 2 * (u & 32);      // B: row = rB0+32h (+128 c=1)

    // fragment-read constants (32x32x16: lane -> row=lane&31, k=(lane>>5)*8+e)
    const int r31  = lane & 31;
    const int l5   = lane >> 5;                    // k-half
    const int sw   = (r31 ^ (r31 >> 2)) & 7;       // swz2 of compacted row
    const int ck0  = ((0 + l5) ^ sw) << 4;
    const int ck1  = ((2 + l5) ^ sw) << 4;
    const int ck2  = ((4 + l5) ^ sw) << 4;
    const int ck3  = ((6 + l5) ^ sw) << 4;
    const int arow = (wm * 64 + r31) * 128;        // A compacted-row byte base
    const int brow = (wn * 32 + r31) * 128;        // B compacted-row byte base

    f32x16 acc[4][2];
#pragma unroll
    for (int i = 0; i < 4; ++i)
#pragma unroll
        for (int j = 0; j < 2; ++j)
#pragma unroll
            for (int r = 0; r < 16; ++r) acc[i][j][r] = 0.f;

    short8 af[2][4], bf0[4], bf1[4];

    auto STAGE_A = [&](int buf, int h, int kt) {
        const char* base; int kb, ko;
        if (NTZ == 0 || kt < NTX) { base = Xb; kb = KBX; ko = kt * 128; }
        else                      { base = Zb; kb = KBZ; ko = (kt - NTX) * 128; }
        char* lp = &lds[buf][0][h][0] + t * 16;
        const size_t go = (size_t)(rA0 + 64 * h) * kb + ko + gb16;
        g2lds16(base + go, lp);
        g2lds16(base + go + (size_t)128 * kb, lp + 8192);
    };
    auto STAGE_B = [&](int buf, int h, int kt) {
        const char* base; int kb, ko;
        if (NTZ == 0 || kt < NTX) { base = Wb; kb = KBX; ko = kt * 128; }
        else                      { base = Sb; kb = KBZ; ko = (kt - NTX) * 128; }
        char* lp = &lds[buf][1][h][0] + t * 16;
        const size_t go = (size_t)(rB0 + 32 * h) * kb + ko + gb16;
        g2lds16(base + go, lp);
        g2lds16(base + go + (size_t)128 * kb, lp + 8192);
    };

    // prologue: stage tile0 (buf0) + tile1 (buf1) fully; drain tile0 (oldest
    // 8 of 16); barrier; pre-read bf0 <- tile0.Bh0 (drained by p1's WL0).
    STAGE_A(0, 0, 0); STAGE_B(0, 0, 0); STAGE_A(0, 1, 0); STAGE_B(0, 1, 0);
    STAGE_A(1, 0, 1); STAGE_B(1, 0, 1); STAGE_A(1, 1, 1); STAGE_B(1, 1, 1);
    VM8;
    __builtin_amdgcn_s_barrier();
    __builtin_amdgcn_sched_barrier(0);
    LOAD_B(0, 0, bf0);

    // main loop (ledger in header).
#pragma unroll 1
    for (int it = 0; it < NI - 1; ++it) {
        const int c = 2 * it + 2, d = 2 * it + 3;
        PHASE(LOAD_A(0,0); LOAD_B(0,1,bf1),
              NOPX,                                            WL0,  0,0, bf0, NOPX);
        PHASE(NOPX,
              (STAGE_A(0,0,c), STAGE_B(0,0,c), STAGE_B(0,1,c)), NOPX, 0,1, bf1, NOPX);
        PHASE(LOAD_A(0,1),
              NOPX,                                            WL0,  1,0, bf0, VM6);
        PHASE(LOAD_B(1,0,bf0),
              STAGE_A(0,1,c),                                  NOPX, 1,1, bf1, NOPX);
        PHASE(LOAD_A(1,0); LOAD_B(1,1,bf1),
              NOPX,                                            WL0,  0,0, bf0, NOPX);
        PHASE(NOPX,
              (STAGE_A(1,0,d), STAGE_B(1,0,d), STAGE_B(1,1,d)), NOPX, 0,1, bf1, NOPX);
        PHASE(LOAD_A(1,1),
              NOPX,                                            WL0,  1,0, bf0, VM6);
        PHASE(LOAD_B(0,0,bf0),
              STAGE_A(1,1,d),                                  NOPX, 1,1, bf1, NOPX);
    }
    {   // last window: no stages; VM0 at p3 drains tile NT-1; no p8 pre-read.
        PHASE(LOAD_A(0,0); LOAD_B(0,1,bf1), NOPX, WL0,  0,0, bf0, NOPX);
        PHASE(NOPX,                         NOPX, NOPX, 0,1, bf1, NOPX);
        PHASE(LOAD_A(0,1),                  NOPX, WL0,  1,0, bf0, VM0);
        PHASE(LOAD_B(1,0,bf0),              NOPX, NOPX, 1,1, bf1, NOPX);
        PHASE(LOAD_A(1,0); LOAD_B(1,1,bf1), NOPX, WL0,  0,0, bf0, NOPX);
        PHASE(NOPX,                         NOPX, NOPX, 0,1, bf1, NOPX);
        PHASE(LOAD_A(1,1),                  NOPX, WL0,  1,0, bf0, NOPX);
        PHASE(NOPX,                         NOPX, NOPX, 1,1, bf1, NOPX);
    }

    // epilogue. 32x32 C/D: col = lane&31, row = (reg&3)+8*(reg>>2)+4*(lane>>5)
    const int colb = bn * 256 + wn * 64 + r31;
    const int rowb = bm * 256 + wm * 128;
    const float th0 = theta[colb];
    const float th1 = theta[colb + 32];

    if constexpr (LAST) {
        // fp32 direct: 32 lanes x 4B = full 128B line per row-chunk.
#pragma unroll
        for (int MF = 0; MF < 4; ++MF)
#pragma unroll
        for (int reg = 0; reg < 16; ++reg) {
            const int rrow = rowb + MF * 32 + (reg & 3) + 8 * (reg >> 2) + 4 * l5;
#pragma unroll
            for (int h = 0; h < 2; ++h) {
                const float c = acc[MF][h][reg];
                const float a = fabsf(c) - (h ? th1 : th0);
                const float z = a > 0.f ? (c > 0.f ? a : -a) : 0.f;
                Fout[(size_t)rrow * 1024 + colb + h * 32] = z;
            }
        }
    } else {
        // bf16 via per-wave 16KB LDS transpose slab; readback row-linear ->
        // each global store = 8 rows x 128B full lines (no write RMW).
        char* slab = &lds[0][0][0][0] + wave * 16384;
#pragma unroll
        for (int MF = 0; MF < 4; ++MF)
#pragma unroll
        for (int h = 0; h < 2; ++h)
#pragma unroll
        for (int reg = 0; reg < 16; ++reg) {
            const int row = MF * 32 + (reg & 3) + 8 * (reg >> 2) + 4 * l5;
            const int cb  = (h * 64 + r31 * 2) ^ ((row & 7) << 4);
            const float c = acc[MF][h][reg];
            const float a = fabsf(c) - (h ? th1 : th0);
            const float z = a > 0.f ? (c > 0.f ? a : -a) : 0.f;
            __hip_bfloat16 hb = __float2bfloat16(z);
            *(unsigned short*)(slab + row * 128 + cb) = *(const unsigned short*)&hb;
        }
        __builtin_amdgcn_sched_barrier(0);
#pragma unroll
        for (int i = 0; i < 16; ++i) {
            const int r = i * 8 + (lane >> 3);
            const short8 v = *(const short8*)(slab + r * 128 + (((lane & 7) ^ (r & 7)) << 4));
            char* gp = (char*)Zout + (size_t)(rowb + r) * 2048
                     + bn * 512 + wn * 128 + (lane & 7) * 16;
            *(short8*)gp = v;
        }
    }
}

__global__ void __launch_bounds__(256)
cvt4(const float* __restrict__ s, unsigned short* __restrict__ d, int n4)
{
    const int i = blockIdx.x * blockDim.x + threadIdx.x;
    if (i < n4) {
        const float4 v = ((const float4*)s)[i];
        ushort4 o;
        __hip_bfloat16 b;
        b = __float2bfloat16(v.x); o.x = *(unsigned short*)&b;
        b = __float2bfloat16(v.y); o.y = *(unsigned short*)&b;
        b = __float2bfloat16(v.z); o.z = *(unsigned short*)&b;
        b = __float2bfloat16(v.w); o.w = *(unsigned short*)&b;
        ((ushort4*)d)[i] = o;
    }
}

extern "C" void kernel_launch(void* const* d_in, const int* in_sizes, int n_in,
                              void* d_out, int out_size, void* d_ws, size_t ws_size,
                              hipStream_t stream) {
    (void)in_sizes; (void)n_in; (void)out_size; (void)ws_size;
    const float* X     = (const float*)d_in[0];  // 16384 x 256
    const float* We    = (const float*)d_in[1];  // 1024 x 256
    const float* S     = (const float*)d_in[2];  // 1024 x 1024
    const float* theta = (const float*)d_in[3];  // 1024
    float* out = (float*)d_out;                  // 16384 x 1024 fp32

    char* ws = (char*)d_ws;
    unsigned short* S_bf  = (unsigned short*)(ws);                           //  2 MB
    unsigned short* X_bf  = (unsigned short*)(ws + (size_t)2  * 1048576);    //  8 MB
    unsigned short* We_bf = (unsigned short*)(ws + (size_t)10 * 1048576);    // 0.5 MB
    unsigned short* Za    = (unsigned short*)(ws + (size_t)11 * 1048576);    // 32 MB
    unsigned short* Zb    = (unsigned short*)(ws + (size_t)43 * 1048576);    // 32 MB (total 75 MB)

    cvt4<<<dim3(1024), dim3(256), 0, stream>>>(S,  S_bf,  1024 * 1024 / 4);
    cvt4<<<dim3(4096), dim3(256), 0, stream>>>(X,  X_bf,  16384 * 256 / 4);
    cvt4<<<dim3(256),  dim3(256), 0, stream>>>(We, We_bf, 1024 * 256 / 4);

    const dim3 grid(64, 4), blk(512);

    // Z0 = eta(X @ We^T)            (K = 256)
    lista_step<4, 0, false><<<grid, blk, 0, stream>>>(
        X_bf, We_bf, nullptr, nullptr, theta, Za, nullptr);

    // steps 1..15: Z = eta([X,Z] @ [We,S]^T)   (K = 1280), ping-pong bf16
    unsigned short* zin = Za;
    unsigned short* zout = Zb;
    for (int tstep = 1; tstep <= 15; ++tstep) {
        lista_step<4, 16, false><<<grid, blk, 0, stream>>>(
            X_bf, We_bf, zin, S_bf, theta, zout, nullptr);
        unsigned short* tmp = zin; zin = zout; zout = tmp;
    }
    // step 16: write fp32 output directly
    lista_step<4, 16, true><<<grid, blk, 0, stream>>>(
        X_bf, We_bf, zin, S_bf, theta, nullptr, out);
}